// Round 2
// baseline (1765.620 us; speedup 1.0000x reference)
//
#include <hip/hip_runtime.h>
#include <hip/hip_bf16.h>
#include <cmath>

// ---------------------------------------------------------------------------
// IntegerDiscreteFlow on MI355X (gfx950)
// B=8192, D=1024, d2=512, N=2048, F=8 steps.
// State S (8192x1024 f32) updated in place; the [:, ::-1] reversal is an
// orientation bit (logical j <-> stored 1023-j), flipped each step.
// GEMMs in bf16 MFMA 16x16x32, fp32 accumulate.
// R2: XOR-swizzled LDS placement (bank conflicts -> 0).
// R3/R4: double-buffer -> BK=64; G3 emits next step's A (prep_A once).
// R5: ring-3 LDS pipeline for G3 (counted vmcnt across raw s_barrier).
// R7: G1/G2 on 256x256 / BK=64 / 8-wave / 4-phase-per-K-tile schedule.
// R8: exact m201 pipeline discipline: read balance 8/4/8/4 (b01 of tile
//     tau+1 pre-read at tau.ph3, covered by tau.ph2's vmcnt(2)+barrier),
//     B(tau+2)/A(tau+2) staged so the single per-tile vmcnt(2) at ph2 waits
//     only on loads issued >=3 phases earlier (never vmcnt(0) in steady
//     state), explicit s_waitcnt lgkmcnt(0) + sched_barrier(0) before each
//     MFMA cluster (rule #18), setprio(1/0) around MFMA.
// ---------------------------------------------------------------------------

typedef __bf16 bf16_t;
typedef bf16_t bf16x8 __attribute__((ext_vector_type(8)));
typedef float floatx4 __attribute__((ext_vector_type(4)));

#define BQ 8192
#define DD 1024
#define D2 512
#define NH 2048
#define NF 8

__device__ __forceinline__ void gload_lds16(const void* g, void* l) {
    __builtin_amdgcn_global_load_lds(
        (__attribute__((address_space(1))) void*)g,
        (__attribute__((address_space(3))) void*)l, 16, 0, 0);
}

// ---- weight convert+transpose: W (K x N f32, row-major) -> Wt (N x K bf16) --
__global__ __launch_bounds__(256)
void transpose_bf16(const float* __restrict__ W, bf16_t* __restrict__ Wt,
                    int K, int N) {
    __shared__ float tile[32][33];
    size_t fo = (size_t)blockIdx.z * K * N;
    int n0 = blockIdx.x * 32, k0 = blockIdx.y * 32;
    int tx = threadIdx.x & 31, ty = threadIdx.x >> 5;   // 32 x 8
    for (int i = 0; i < 4; i++)
        tile[ty + i*8][tx] = W[fo + (size_t)(k0 + ty + i*8) * N + n0 + tx];
    __syncthreads();
    for (int i = 0; i < 4; i++)
        Wt[fo + (size_t)(n0 + ty + i*8) * K + k0 + tx] = (bf16_t)tile[tx][ty + i*8];
}

// ---- copy x -> S (f32, vectorized) ----
__global__ __launch_bounds__(256)
void copy_x(const float4* __restrict__ x, float4* __restrict__ S) {
    int idx = blockIdx.x * blockDim.x + threadIdx.x;   // 2M threads
    S[idx] = x[idx];
}

// ---- build bf16 A operand (= logical xa) from S, identity orientation ----
__global__ __launch_bounds__(256)
void prep_A(const float* __restrict__ S, bf16_t* __restrict__ Ab) {
    int idx = blockIdx.x * blockDim.x + threadIdx.x;   // over 8192*512
    int m = idx >> 9;
    int j = idx & 511;
    Ab[idx] = (bf16_t)S[(size_t)m * DD + j];
}

// ---- GEMM (ring-3 pipeline, used for G3 / MODE 1 only) ----
// Block tile TM x TN, BK=32, 4 waves (2x2), wave-tile (TM/2) x (TN/2).
// MODE 1: S[m, slot(n)] += rint(acc + bias[n]); Abn[m, 511-n] = new value
template<int MODE, int K, int TM, int TN, int MINW>
__global__ __launch_bounds__(256, MINW)
void gemm_kernel(const bf16_t* __restrict__ A, const bf16_t* __restrict__ Bt,
                 const float* __restrict__ bias,
                 bf16_t* __restrict__ Cout, float* __restrict__ S,
                 bf16_t* __restrict__ Abn,
                 int N, int rflag)
{
    constexpr int IM   = TM / 32;          // i-fragments per wave
    constexpr int JN   = TN / 32;          // j-fragments per wave
    constexpr int NA   = TM / 64;          // A DMA instrs per tile
    constexpr int NBD  = TN / 64;          // B DMA instrs per tile
    constexpr int NDMA = NA + NBD;         // DMA instrs per tile
    constexpr int T    = K / 32;           // K-tiles
    static_assert((T - 1) % 3 == 0, "pipeline triple-unroll needs (T-1)%3==0");
    static_assert(JN % 4 == 0, "bff processed in groups of 4");

    __shared__ __align__(16) bf16_t As[3][TM * 32];
    __shared__ __align__(16) bf16_t Bs[3][TN * 32];

    const int tid  = threadIdx.x;
    const int lane = tid & 63;
    const int wave = tid >> 6;
    const int wm   = wave >> 1;            // 0..1
    const int wn   = wave & 1;             // 0..1
    const int m0   = blockIdx.y * TM;
    const int n0   = blockIdx.x * TN;

    const int srow = tid >> 2;
    const int sq   = ((tid & 3) ^ ((srow >> 1) & 3)) * 8;
    const bf16_t* agp = A  + (size_t)(m0 + srow) * K + sq;
    const bf16_t* bgp = Bt + (size_t)(n0 + srow) * K + sq;

    floatx4 acc[IM][JN];
#pragma unroll
    for (int i = 0; i < IM; i++)
#pragma unroll
        for (int j = 0; j < JN; j++)
            acc[i][j] = (floatx4){0.f, 0.f, 0.f, 0.f};

    const int fr  = lane & 15;
    const int fp8 = ((lane >> 4) ^ ((lane >> 1) & 3)) * 8;

#define ISSUE_TILE(NB)                                                       \
    {                                                                        \
        _Pragma("unroll")                                                    \
        for (int u = 0; u < NA; u++)                                         \
            gload_lds16(agp + (size_t)(u*64) * K, &As[NB][u*2048 + tid*8]);  \
        _Pragma("unroll")                                                    \
        for (int u = 0; u < NBD; u++)                                        \
            gload_lds16(bgp + (size_t)(u*64) * K, &Bs[NB][u*2048 + tid*8]);  \
        agp += 32; bgp += 32;                                                \
    }

#define COMPUTE(CB)                                                          \
    {                                                                        \
        bf16x8 af[IM];                                                       \
        _Pragma("unroll")                                                    \
        for (int i = 0; i < IM; i++)                                         \
            af[i] = *(const bf16x8*)&As[CB][(wm*(TM/2) + i*16 + fr)*32 + fp8];\
        _Pragma("unroll")                                                    \
        for (int g2 = 0; g2 < JN/4; g2++) {                                  \
            bf16x8 bff[4];                                                   \
            _Pragma("unroll")                                                \
            for (int j = 0; j < 4; j++)                                      \
                bff[j] = *(const bf16x8*)                                    \
                    &Bs[CB][(wn*(TN/2) + (g2*4+j)*16 + fr)*32 + fp8];        \
            _Pragma("unroll")                                                \
            for (int i = 0; i < IM; i++)                                     \
                _Pragma("unroll")                                            \
                for (int j = 0; j < 4; j++)                                  \
                    acc[i][g2*4+j] = __builtin_amdgcn_mfma_f32_16x16x32_bf16(\
                                    af[i], bff[j], acc[i][g2*4+j], 0, 0, 0); \
        }                                                                    \
    }

#define PIPE_STEP(NB, CB)                                                    \
    {                                                                        \
        ISSUE_TILE(NB);                                                      \
        __builtin_amdgcn_s_waitcnt(0x0F70 | NDMA);  /* prev tile landed */   \
        __builtin_amdgcn_s_barrier();                                        \
        COMPUTE(CB);                                                         \
    }

    ISSUE_TILE(0);

#pragma unroll 1
    for (int g = 0; g < (T - 1) / 3; ++g) {
        PIPE_STEP(1, 0);
        PIPE_STEP(2, 1);
        PIPE_STEP(0, 2);
    }
    __builtin_amdgcn_s_waitcnt(0x0F70);            // vmcnt(0)
    __builtin_amdgcn_s_barrier();
    COMPUTE(0);

#undef PIPE_STEP
#undef COMPUTE
#undef ISSUE_TILE

    const int ccol  = lane & 15;
    const int crow4 = (lane >> 4) * 4;
#pragma unroll
    for (int j = 0; j < JN; j++) {
        int col = n0 + wn*(TN/2) + j*16 + ccol;
        float bj = bias[col];
        if (MODE == 0) {
#pragma unroll
            for (int i = 0; i < IM; i++) {
#pragma unroll
                for (int r = 0; r < 4; r++) {
                    int row = m0 + wm*(TM/2) + i*16 + crow4 + r;
                    float v = acc[i][j][r] + bj;
                    v = v >= 0.f ? v : 0.01f * v;
                    Cout[(size_t)row * N + col] = (bf16_t)v;
                }
            }
        } else {
            int slot = rflag ? (511 - col) : (512 + col);
            int aj   = 511 - col;          // next step's xa = reverse(yb)
#pragma unroll
            for (int i = 0; i < IM; i++) {
#pragma unroll
                for (int r = 0; r < 4; r++) {
                    int row = m0 + wm*(TM/2) + i*16 + crow4 + r;
                    float t = acc[i][j][r] + bj;
                    float nv = S[(size_t)row * DD + slot] + rintf(t);
                    S[(size_t)row * DD + slot] = nv;
                    Abn[(size_t)row * D2 + aj] = (bf16_t)nv;
                }
            }
        }
    }
}

// ---------------------------------------------------------------------------
// 256x256 / BK=64 / 8-wave GEMM, m201-faithful pipeline. MODE-0 epilogue:
// Cout = bf16(leaky_relu(A @ Bt^T + bias)).
//
// Per-tile schedule (tau, buf c = tau&1; all WARs barrier-verified):
//  ph0: ds_read af(i0..3)          (8)                       | MFMA Q(i0-3,j0-1) w/ b01
//  ph1: ds_read b23                (4)                       | MFMA Q(i0-3,j2-3)
//  ph2: ds_read af(i4..7)          (8); stage B(t+2)h0 -> c  | MFMA Q(i4-7,j2-3); vmcnt(2)
//  ph3: stage A(t+2)h0,h1 + B(t+2)h1 -> c                    | MFMA Q(i4-7,j0-1);
//       ds_read b01 of tile t+1 from c^1  (4)   [covered by ph2 vmcnt+barrier]
// Steady-state vmcnt(2) waits on A(t+1)h1 / B(t+1)h1 issued at (t-1).ph3 —
// 3 phases earlier; never vmcnt(0) except the tail (tau == T-2).
// Each phase: {reads; stages; s_barrier; lgkmcnt(0); sched_barrier(0);
// setprio(1); 16 MFMA; setprio(0); [ph2: vmcnt]; s_barrier}.
// Swizzle: stored chunk p = q ^ (row&7), pre-swizzled global source, linear
// LDS dst, same XOR on ds_read address (<=2-way aliasing, measured 0).
// ---------------------------------------------------------------------------
#define LGKM0_FENCE()                                        \
    {                                                        \
        asm volatile("s_waitcnt lgkmcnt(0)" ::: "memory");   \
        __builtin_amdgcn_sched_barrier(0);                   \
    }

template<int K>
__global__ __launch_bounds__(512, 2)
void gemm256_kernel(const bf16_t* __restrict__ A, const bf16_t* __restrict__ Bt,
                    const float* __restrict__ bias, bf16_t* __restrict__ Cout,
                    int N)
{
    constexpr int T = K / 64;              // K-tiles
    static_assert(T >= 4, "pipeline needs >=4 K-tiles");

    __shared__ __align__(16) bf16_t As[2][16384];   // [buf][256 rows x 64]
    __shared__ __align__(16) bf16_t Bs[2][16384];

    const int tid  = threadIdx.x;          // 0..511
    const int lane = tid & 63;
    const int wave = tid >> 6;             // 0..7
    const int wm   = wave >> 2;            // 0..1  (M half)
    const int wn   = wave & 3;             // 0..3  (N quarter)
    const int m0   = blockIdx.y * 256;
    const int n0   = blockIdx.x * 256;

    // staging source map: thread t -> row (t>>3) within 64-row DMA slab,
    // fetched chunk q = (t&7) ^ (row&7); LDS dst linear at t*16 bytes.
    const int srow = tid >> 3;             // 0..63
    const int sq   = ((tid & 7) ^ (srow & 7)) * 8;
    const bf16_t* agp = A  + (size_t)(m0 + srow) * K + sq;
    const bf16_t* bgp = Bt + (size_t)(n0 + srow) * K + sq;
    const int ldst = tid * 8;              // elements

#define STAGE_A(H, TILE, BUF)                                                 \
    {                                                                         \
        _Pragma("unroll")                                                     \
        for (int u = 0; u < 2; ++u)                                           \
            gload_lds16(agp + (size_t)((H)*128 + u*64) * K + (size_t)(TILE)*64,\
                        &As[BUF][(H)*8192 + u*4096 + ldst]);                  \
    }
#define STAGE_B(H, TILE, BUF)                                                 \
    {                                                                         \
        _Pragma("unroll")                                                     \
        for (int u = 0; u < 2; ++u)                                           \
            gload_lds16(bgp + (size_t)((H)*128 + u*64) * K + (size_t)(TILE)*64,\
                        &Bs[BUF][(H)*8192 + u*4096 + ldst]);                  \
    }
#define MFMA16(D, Av, Bv) \
    D = __builtin_amdgcn_mfma_f32_16x16x32_bf16(Av, Bv, D, 0, 0, 0)

    floatx4 acc[8][4];
#pragma unroll
    for (int i = 0; i < 8; ++i)
#pragma unroll
        for (int j = 0; j < 4; ++j)
            acc[i][j] = (floatx4){0.f, 0.f, 0.f, 0.f};

    // fragment read offsets: row r -> r*64 elems; chunk (ks*4+qh)^l7
    const int fr = lane & 15;
    const int l7 = lane & 7;
    const int qh = lane >> 4;
    const int ra = (wm*128 + fr) * 64;
    const int rb = (wn*64  + fr) * 64;
    const int c0 = ((qh    ) ^ l7) * 8;    // ks=0
    const int c1 = ((qh + 4) ^ l7) * 8;    // ks=1

    // prologue: tile0 (8 loads), then tile1 staged in the steady-state
    // pattern (B h0 first, then A h0/h1 + B h1) = 8 more loads.
    STAGE_B(0, 0, 0); STAGE_B(1, 0, 0);
    STAGE_A(0, 0, 0); STAGE_A(1, 0, 0);
    STAGE_B(0, 1, 1);
    STAGE_A(0, 1, 1); STAGE_A(1, 1, 1); STAGE_B(1, 1, 1);
    __builtin_amdgcn_s_waitcnt(0x0F78);    // vmcnt(8): tile 0 landed
    __builtin_amdgcn_s_barrier();          // all waves' tile-0 portions landed
    __builtin_amdgcn_sched_barrier(0);

    bf16x8 b01[2][2];                      // loop-carried: b01 of current tile
#pragma unroll
    for (int j = 0; j < 2; ++j) {
        b01[j][0] = *(const bf16x8*)&Bs[0][rb + j*1024 + c0];
        b01[j][1] = *(const bf16x8*)&Bs[0][rb + j*1024 + c1];
    }

#pragma unroll 1
    for (int tau = 0; tau < T; ++tau) {
        const int c = tau & 1;
        const bf16_t* Ac = As[c];
        const bf16_t* Bc = Bs[c];
        const bf16_t* Bn = Bs[c ^ 1];
        bf16x8 af[4][2], b23[2][2];

        // ---- phase 0: read af(i0..3); MFMA Q(i0-3, j0-1) ----
#pragma unroll
        for (int i = 0; i < 4; ++i) {
            af[i][0] = *(const bf16x8*)&Ac[ra + i*1024 + c0];
            af[i][1] = *(const bf16x8*)&Ac[ra + i*1024 + c1];
        }
        __builtin_amdgcn_s_barrier();
        LGKM0_FENCE();
        __builtin_amdgcn_s_setprio(1);
#pragma unroll
        for (int i = 0; i < 4; ++i)
#pragma unroll
            for (int j = 0; j < 2; ++j) {
                MFMA16(acc[i][j], af[i][0], b01[j][0]);
                MFMA16(acc[i][j], af[i][1], b01[j][1]);
            }
        __builtin_amdgcn_s_setprio(0);
        __builtin_amdgcn_s_barrier();

        // ---- phase 1: read b23; MFMA Q(i0-3, j2-3) ----
#pragma unroll
        for (int j = 0; j < 2; ++j) {
            b23[j][0] = *(const bf16x8*)&Bc[rb + (j+2)*1024 + c0];
            b23[j][1] = *(const bf16x8*)&Bc[rb + (j+2)*1024 + c1];
        }
        __builtin_amdgcn_s_barrier();
        LGKM0_FENCE();
        __builtin_amdgcn_s_setprio(1);
#pragma unroll
        for (int i = 0; i < 4; ++i)
#pragma unroll
            for (int j = 0; j < 2; ++j) {
                MFMA16(acc[i][j+2], af[i][0], b23[j][0]);
                MFMA16(acc[i][j+2], af[i][1], b23[j][1]);
            }
        __builtin_amdgcn_s_setprio(0);
        __builtin_amdgcn_s_barrier();

        // ---- phase 2: read af(i4..7); stage B(t+2)h0; MFMA; vmcnt ----
#pragma unroll
        for (int i = 0; i < 4; ++i) {
            af[i][0] = *(const bf16x8*)&Ac[ra + (i+4)*1024 + c0];
            af[i][1] = *(const bf16x8*)&Ac[ra + (i+4)*1024 + c1];
        }
        if (tau + 2 < T) STAGE_B(0, tau + 2, c);
        __builtin_amdgcn_s_barrier();
        LGKM0_FENCE();
        __builtin_amdgcn_s_setprio(1);
#pragma unroll
        for (int i = 0; i < 4; ++i)
#pragma unroll
            for (int j = 0; j < 2; ++j) {
                MFMA16(acc[i+4][j+2], af[i][0], b23[j][0]);
                MFMA16(acc[i+4][j+2], af[i][1], b23[j][1]);
            }
        __builtin_amdgcn_s_setprio(0);
        // single per-tile wait: tile t+1 fully landed (oldest waited load
        // was issued at (t-1).ph3 — 3 phases ago). Tail: drain.
        if (tau < T - 2) __builtin_amdgcn_s_waitcnt(0x0F72); // vmcnt(2)
        else             __builtin_amdgcn_s_waitcnt(0x0F70); // vmcnt(0)
        __builtin_amdgcn_s_barrier();      // cross-wave: t+1 visible to all

        // ---- phase 3: stage A(t+2)h0,h1 + B(t+2)h1; MFMA Q(i4-7, j0-1);
        //      then pre-read b01 of tile t+1 from buf c^1 ----
        if (tau + 2 < T) {
            STAGE_A(0, tau + 2, c);
            STAGE_A(1, tau + 2, c);
            STAGE_B(1, tau + 2, c);
        }
        __builtin_amdgcn_s_barrier();
        LGKM0_FENCE();
        __builtin_amdgcn_s_setprio(1);
#pragma unroll
        for (int i = 0; i < 4; ++i)
#pragma unroll
            for (int j = 0; j < 2; ++j) {
                MFMA16(acc[i+4][j], af[i][0], b01[j][0]);
                MFMA16(acc[i+4][j], af[i][1], b01[j][1]);
            }
        __builtin_amdgcn_s_setprio(0);
        if (tau + 1 < T) {
#pragma unroll
            for (int j = 0; j < 2; ++j) {
                b01[j][0] = *(const bf16x8*)&Bn[rb + j*1024 + c0];
                b01[j][1] = *(const bf16x8*)&Bn[rb + j*1024 + c1];
            }
        }
        __builtin_amdgcn_sched_barrier(0);
        __builtin_amdgcn_s_barrier();
    }

#undef STAGE_A
#undef STAGE_B
#undef MFMA16

    // epilogue: C[row, col], col = lane&15, row = (lane>>4)*4 + r (m89 layout)
    const int ccol  = lane & 15;
    const int crow4 = (lane >> 4) * 4;
#pragma unroll
    for (int j = 0; j < 4; ++j) {
        int col = n0 + wn*64 + j*16 + ccol;
        float bj = bias[col];
#pragma unroll
        for (int i = 0; i < 8; ++i) {
#pragma unroll
            for (int r = 0; r < 4; ++r) {
                int row = m0 + wm*128 + i*16 + crow4 + r;
                float v = acc[i][j][r] + bj;
                v = v >= 0.f ? v : 0.01f * v;
                Cout[(size_t)row * N + col] = (bf16_t)v;
            }
        }
    }
}

// ---- final discretized-logistic NLL reduction ----
__global__ __launch_bounds__(256)
void reduce_nll(const float* __restrict__ S, const float* __restrict__ mean,
                const float* __restrict__ log_scale, float* __restrict__ out)
{
    float local = 0.f;
    const int total = BQ * DD;
    for (int idx = blockIdx.x * blockDim.x + threadIdx.x; idx < total;
         idx += gridDim.x * blockDim.x) {
        int j = idx & (DD - 1);
        float z  = S[idx];
        float mu = mean[j];
        float sc = expf(log_scale[j]);
        float ua = (z + 0.5f - mu) / sc;
        float ub = (z - 0.5f - mu) / sc;
        float la = fminf(ua, 0.f) - log1pf(expf(-fabsf(ua)));
        float lb = fminf(ub, 0.f) - log1pf(expf(-fabsf(ub)));
        float lp = la + logf(1.0f - expf(lb - la) + 1e-8f);
        local += lp;
    }
    __shared__ float red[256];
    red[threadIdx.x] = local;
    __syncthreads();
    for (int s = 128; s > 0; s >>= 1) {
        if (threadIdx.x < s) red[threadIdx.x] += red[threadIdx.x + s];
        __syncthreads();
    }
    if (threadIdx.x == 0) atomicAdd(out, -red[0] * (1.0f / (float)BQ));
}

extern "C" void kernel_launch(void* const* d_in, const int* in_sizes, int n_in,
                              void* d_out, int out_size, void* d_ws, size_t ws_size,
                              hipStream_t stream)
{
    const float* x   = (const float*)d_in[0];
    const float* W1  = (const float*)d_in[1];
    const float* b1  = (const float*)d_in[2];
    const float* W2  = (const float*)d_in[3];
    const float* b2  = (const float*)d_in[4];
    const float* W3  = (const float*)d_in[5];
    const float* b3  = (const float*)d_in[6];
    const float* mean = (const float*)d_in[7];
    const float* lsc  = (const float*)d_in[8];

    char* ws = (char*)d_ws;
    bf16_t* Wt1 = (bf16_t*)ws; ws += (size_t)NF * NH * D2 * 2;   // 16 MB (NxK = 2048x512)
    bf16_t* Wt2 = (bf16_t*)ws; ws += (size_t)NF * NH * NH * 2;   // 64 MB
    bf16_t* Wt3 = (bf16_t*)ws; ws += (size_t)NF * D2 * NH * 2;   // 16 MB (512x2048)
    float*  S   = (float*)ws;  ws += (size_t)BQ * DD * 4;        // 32 MB
    bf16_t* Ab  = (bf16_t*)ws; ws += (size_t)BQ * D2 * 2;        //  8 MB
    bf16_t* H1  = (bf16_t*)ws; ws += (size_t)BQ * NH * 2;        // 32 MB
    bf16_t* H2  = (bf16_t*)ws;                                   // 32 MB  (total 200 MB)

    hipMemsetAsync(d_out, 0, sizeof(float), stream);

    dim3 blk(256);
    // W1: (K=512, N=2048) -> Wt1 (2048x512)
    transpose_bf16<<<dim3(NH/32, D2/32, NF), blk, 0, stream>>>(W1, Wt1, D2, NH);
    // W2: (2048, 2048)
    transpose_bf16<<<dim3(NH/32, NH/32, NF), blk, 0, stream>>>(W2, Wt2, NH, NH);
    // W3: (K=2048, N=512) -> Wt3 (512x2048)
    transpose_bf16<<<dim3(D2/32, NH/32, NF), blk, 0, stream>>>(W3, Wt3, NH, D2);

    copy_x<<<BQ * DD / 4 / 256, blk, 0, stream>>>((const float4*)x, (float4*)S);
    prep_A<<<BQ * D2 / 256, blk, 0, stream>>>(S, Ab);   // step 0 only

    for (int f = 0; f < NF; ++f) {
        int r = f & 1;
        // G1: (8192 x 512) @ (512 x 2048) -> H1   [256x256 pipeline, 256 blocks]
        gemm256_kernel<D2><<<dim3(NH/256, BQ/256), dim3(512), 0, stream>>>(
            Ab, Wt1 + (size_t)f * NH * D2, b1 + (size_t)f * NH, H1, NH);
        // G2: (8192 x 2048) @ (2048 x 2048) -> H2 [256x256 pipeline, 256 blocks]
        gemm256_kernel<NH><<<dim3(NH/256, BQ/256), dim3(512), 0, stream>>>(
            H1, Wt2 + (size_t)f * NH * NH, b2 + (size_t)f * NH, H2, NH);
        // G3: (8192 x 2048) @ (2048 x 512), 64x128 tiles -> S + next-A emit
        gemm_kernel<1, NH, 64, 128, 3><<<dim3(D2/128, BQ/64), blk, 0, stream>>>(
            H2, Wt3 + (size_t)f * D2 * NH, b3 + (size_t)f * D2, nullptr, S,
            Ab, D2, r);
    }

    reduce_nll<<<2048, blk, 0, stream>>>(S, mean, lsc, (float*)d_out);
}

// Round 4
// 1586.761 us; speedup vs baseline: 1.1127x; 1.1127x over previous
//
#include <hip/hip_runtime.h>
#include <hip/hip_bf16.h>
#include <cmath>

// ---------------------------------------------------------------------------
// IntegerDiscreteFlow on MI355X (gfx950)
// B=8192, D=1024, d2=512, N=2048, F=8 steps.
// State S (8192x1024 f32) updated in place; the [:, ::-1] reversal is an
// orientation bit (logical j <-> stored 1023-j), flipped each step.
// GEMMs in bf16 MFMA 16x16x32, fp32 accumulate.
// R2: XOR-swizzled LDS placement (bank conflicts -> 0).
// R5: ring-3 LDS pipeline for G3 (counted vmcnt across raw s_barrier).
// R9: 8-phase ports (R7/R8) abandoned — reproduced m232's failed-port result
//     (642-764 TF vs R6's 832). Back to the R6 family; the counters say
//     latency-bound (MFMA 33%, LDS ~50%, HBM 28%, occupancy 18.5%), so this
//     round buys concurrency: G1/G2 move to 128x128 tiles / 4 waves /
//     2-buffer LDS (32 KB) -> grid 1024 = 4 blocks/CU, 16 waves/CU (was
//     8 waves/CU). 2-buf loop keeps 1 barrier/tile: STAGE(t+1) issued before
//     COMPUTE(t), then vmcnt(0)+barrier (loads hidden under a full compute
//     phase; WAR separation provided by the single barrier).
//     G3 unchanged (grid-capped). copy_x+prep_A fused.
// R10: identical resubmit of R9 — round 3 failed on container acquisition
//     (infra), no counters; no evidence to change anything yet.
// ---------------------------------------------------------------------------

typedef __bf16 bf16_t;
typedef bf16_t bf16x4 __attribute__((ext_vector_type(4)));
typedef bf16_t bf16x8 __attribute__((ext_vector_type(8)));
typedef float floatx4 __attribute__((ext_vector_type(4)));

#define BQ 8192
#define DD 1024
#define D2 512
#define NH 2048
#define NF 8

__device__ __forceinline__ void gload_lds16(const void* g, void* l) {
    __builtin_amdgcn_global_load_lds(
        (__attribute__((address_space(1))) void*)g,
        (__attribute__((address_space(3))) void*)l, 16, 0, 0);
}

// ---- weight convert+transpose: W (K x N f32, row-major) -> Wt (N x K bf16) --
__global__ __launch_bounds__(256)
void transpose_bf16(const float* __restrict__ W, bf16_t* __restrict__ Wt,
                    int K, int N) {
    __shared__ float tile[32][33];
    size_t fo = (size_t)blockIdx.z * K * N;
    int n0 = blockIdx.x * 32, k0 = blockIdx.y * 32;
    int tx = threadIdx.x & 31, ty = threadIdx.x >> 5;   // 32 x 8
    for (int i = 0; i < 4; i++)
        tile[ty + i*8][tx] = W[fo + (size_t)(k0 + ty + i*8) * N + n0 + tx];
    __syncthreads();
    for (int i = 0; i < 4; i++)
        Wt[fo + (size_t)(n0 + ty + i*8) * K + k0 + tx] = (bf16_t)tile[tx][ty + i*8];
}

// ---- fused: S = x (f32 copy) and Ab = bf16(xa) for step 0 ----
__global__ __launch_bounds__(256)
void init_SA(const float4* __restrict__ x, float4* __restrict__ S,
             bf16_t* __restrict__ Ab) {
    int idx = blockIdx.x * blockDim.x + threadIdx.x;   // over BQ*DD/4 = 2M
    float4 v = x[idx];
    S[idx] = v;
    int col4 = idx & (DD/4 - 1);                       // 0..255 (j = col4*4)
    if (col4 < D2/4) {
        int m = idx >> 8;
        bf16x4 p;
        p[0] = (bf16_t)v.x; p[1] = (bf16_t)v.y;
        p[2] = (bf16_t)v.z; p[3] = (bf16_t)v.w;
        ((bf16x4*)Ab)[(size_t)m * (D2/4) + col4] = p;
    }
}

// ---- GEMM (ring-3 pipeline, used for G3 / MODE 1) ----
// Block tile TM x TN, BK=32, 4 waves (2x2), wave-tile (TM/2) x (TN/2).
// MODE 1: S[m, slot(n)] += rint(acc + bias[n]); Abn[m, 511-n] = new value
template<int MODE, int K, int TM, int TN, int MINW>
__global__ __launch_bounds__(256, MINW)
void gemm_kernel(const bf16_t* __restrict__ A, const bf16_t* __restrict__ Bt,
                 const float* __restrict__ bias,
                 bf16_t* __restrict__ Cout, float* __restrict__ S,
                 bf16_t* __restrict__ Abn,
                 int N, int rflag)
{
    constexpr int IM   = TM / 32;          // i-fragments per wave
    constexpr int JN   = TN / 32;          // j-fragments per wave
    constexpr int NA   = TM / 64;          // A DMA instrs per tile
    constexpr int NBD  = TN / 64;          // B DMA instrs per tile
    constexpr int NDMA = NA + NBD;         // DMA instrs per tile
    constexpr int T    = K / 32;           // K-tiles
    static_assert((T - 1) % 3 == 0, "pipeline triple-unroll needs (T-1)%3==0");
    static_assert(JN % 4 == 0, "bff processed in groups of 4");

    __shared__ __align__(16) bf16_t As[3][TM * 32];
    __shared__ __align__(16) bf16_t Bs[3][TN * 32];

    const int tid  = threadIdx.x;
    const int lane = tid & 63;
    const int wave = tid >> 6;
    const int wm   = wave >> 1;            // 0..1
    const int wn   = wave & 1;             // 0..1
    const int m0   = blockIdx.y * TM;
    const int n0   = blockIdx.x * TN;

    const int srow = tid >> 2;
    const int sq   = ((tid & 3) ^ ((srow >> 1) & 3)) * 8;
    const bf16_t* agp = A  + (size_t)(m0 + srow) * K + sq;
    const bf16_t* bgp = Bt + (size_t)(n0 + srow) * K + sq;

    floatx4 acc[IM][JN];
#pragma unroll
    for (int i = 0; i < IM; i++)
#pragma unroll
        for (int j = 0; j < JN; j++)
            acc[i][j] = (floatx4){0.f, 0.f, 0.f, 0.f};

    const int fr  = lane & 15;
    const int fp8 = ((lane >> 4) ^ ((lane >> 1) & 3)) * 8;

#define ISSUE_TILE(NB)                                                       \
    {                                                                        \
        _Pragma("unroll")                                                    \
        for (int u = 0; u < NA; u++)                                         \
            gload_lds16(agp + (size_t)(u*64) * K, &As[NB][u*2048 + tid*8]);  \
        _Pragma("unroll")                                                    \
        for (int u = 0; u < NBD; u++)                                        \
            gload_lds16(bgp + (size_t)(u*64) * K, &Bs[NB][u*2048 + tid*8]);  \
        agp += 32; bgp += 32;                                                \
    }

#define COMPUTE(CB)                                                          \
    {                                                                        \
        bf16x8 af[IM];                                                       \
        _Pragma("unroll")                                                    \
        for (int i = 0; i < IM; i++)                                         \
            af[i] = *(const bf16x8*)&As[CB][(wm*(TM/2) + i*16 + fr)*32 + fp8];\
        _Pragma("unroll")                                                    \
        for (int g2 = 0; g2 < JN/4; g2++) {                                  \
            bf16x8 bff[4];                                                   \
            _Pragma("unroll")                                                \
            for (int j = 0; j < 4; j++)                                      \
                bff[j] = *(const bf16x8*)                                    \
                    &Bs[CB][(wn*(TN/2) + (g2*4+j)*16 + fr)*32 + fp8];        \
            _Pragma("unroll")                                                \
            for (int i = 0; i < IM; i++)                                     \
                _Pragma("unroll")                                            \
                for (int j = 0; j < 4; j++)                                  \
                    acc[i][g2*4+j] = __builtin_amdgcn_mfma_f32_16x16x32_bf16(\
                                    af[i], bff[j], acc[i][g2*4+j], 0, 0, 0); \
        }                                                                    \
    }

#define PIPE_STEP(NB, CB)                                                    \
    {                                                                        \
        ISSUE_TILE(NB);                                                      \
        __builtin_amdgcn_s_waitcnt(0x0F70 | NDMA);  /* prev tile landed */   \
        __builtin_amdgcn_s_barrier();                                        \
        COMPUTE(CB);                                                         \
    }

    ISSUE_TILE(0);

#pragma unroll 1
    for (int g = 0; g < (T - 1) / 3; ++g) {
        PIPE_STEP(1, 0);
        PIPE_STEP(2, 1);
        PIPE_STEP(0, 2);
    }
    __builtin_amdgcn_s_waitcnt(0x0F70);            // vmcnt(0)
    __builtin_amdgcn_s_barrier();
    COMPUTE(0);

#undef PIPE_STEP
#undef COMPUTE
#undef ISSUE_TILE

    const int ccol  = lane & 15;
    const int crow4 = (lane >> 4) * 4;
#pragma unroll
    for (int j = 0; j < JN; j++) {
        int col = n0 + wn*(TN/2) + j*16 + ccol;
        float bj = bias[col];
        if (MODE == 0) {
#pragma unroll
            for (int i = 0; i < IM; i++) {
#pragma unroll
                for (int r = 0; r < 4; r++) {
                    int row = m0 + wm*(TM/2) + i*16 + crow4 + r;
                    float v = acc[i][j][r] + bj;
                    v = v >= 0.f ? v : 0.01f * v;
                    Cout[(size_t)row * N + col] = (bf16_t)v;
                }
            }
        } else {
            int slot = rflag ? (511 - col) : (512 + col);
            int aj   = 511 - col;          // next step's xa = reverse(yb)
#pragma unroll
            for (int i = 0; i < IM; i++) {
#pragma unroll
                for (int r = 0; r < 4; r++) {
                    int row = m0 + wm*(TM/2) + i*16 + crow4 + r;
                    float t = acc[i][j][r] + bj;
                    float nv = S[(size_t)row * DD + slot] + rintf(t);
                    S[(size_t)row * DD + slot] = nv;
                    Abn[(size_t)row * D2 + aj] = (bf16_t)nv;
                }
            }
        }
    }
}

// ---------------------------------------------------------------------------
// G1/G2 GEMM: 128x128 tile, BK=32, 4 waves (2x2, wave-tile 64x64), 2-buffer
// LDS (32 KB) -> 4 blocks/CU resident (grid 1024), 16 waves/CU.
// Loop: { STAGE(t+1 -> b^1); COMPUTE(t, b); vmcnt(0); barrier; } — one
// barrier per tile; t+1's loads hide under COMPUTE(t). WAR: STAGE(t+1->b^1)
// happens after the barrier that ends iter t-1, i.e. after every wave
// finished COMPUTE(t-1, b^1).  Epilogue: bf16(leaky_relu(acc + bias)).
// Same XOR staging/fragment swizzle as gemm_kernel (bank conflicts = 0).
// ---------------------------------------------------------------------------
template<int K, int TM, int TN>
__global__ __launch_bounds__(256, 2)
void gemm2b_kernel(const bf16_t* __restrict__ A, const bf16_t* __restrict__ Bt,
                   const float* __restrict__ bias, bf16_t* __restrict__ Cout,
                   int N)
{
    constexpr int IM   = TM / 32;          // i-fragments per wave
    constexpr int JN   = TN / 32;          // j-fragments per wave
    constexpr int NA   = TM / 64;
    constexpr int NBD  = TN / 64;
    constexpr int T    = K / 32;
    static_assert(T >= 2, "need >=2 K-tiles");
    static_assert(JN % 4 == 0, "bff processed in groups of 4");

    __shared__ __align__(16) bf16_t As[2][TM * 32];
    __shared__ __align__(16) bf16_t Bs[2][TN * 32];

    const int tid  = threadIdx.x;
    const int lane = tid & 63;
    const int wave = tid >> 6;
    const int wm   = wave >> 1;            // 0..1
    const int wn   = wave & 1;             // 0..1
    const int m0   = blockIdx.y * TM;
    const int n0   = blockIdx.x * TN;

    const int srow = tid >> 2;
    const int sq   = ((tid & 3) ^ ((srow >> 1) & 3)) * 8;
    const bf16_t* agp = A  + (size_t)(m0 + srow) * K + sq;
    const bf16_t* bgp = Bt + (size_t)(n0 + srow) * K + sq;

    floatx4 acc[IM][JN];
#pragma unroll
    for (int i = 0; i < IM; i++)
#pragma unroll
        for (int j = 0; j < JN; j++)
            acc[i][j] = (floatx4){0.f, 0.f, 0.f, 0.f};

    const int fr  = lane & 15;
    const int fp8 = ((lane >> 4) ^ ((lane >> 1) & 3)) * 8;

#define ISSUE_TILE(NB)                                                       \
    {                                                                        \
        _Pragma("unroll")                                                    \
        for (int u = 0; u < NA; u++)                                         \
            gload_lds16(agp + (size_t)(u*64) * K, &As[NB][u*2048 + tid*8]);  \
        _Pragma("unroll")                                                    \
        for (int u = 0; u < NBD; u++)                                        \
            gload_lds16(bgp + (size_t)(u*64) * K, &Bs[NB][u*2048 + tid*8]);  \
        agp += 32; bgp += 32;                                                \
    }

#define COMPUTE(CB)                                                          \
    {                                                                        \
        bf16x8 af[IM];                                                       \
        _Pragma("unroll")                                                    \
        for (int i = 0; i < IM; i++)                                         \
            af[i] = *(const bf16x8*)&As[CB][(wm*(TM/2) + i*16 + fr)*32 + fp8];\
        _Pragma("unroll")                                                    \
        for (int g2 = 0; g2 < JN/4; g2++) {                                  \
            bf16x8 bff[4];                                                   \
            _Pragma("unroll")                                                \
            for (int j = 0; j < 4; j++)                                      \
                bff[j] = *(const bf16x8*)                                    \
                    &Bs[CB][(wn*(TN/2) + (g2*4+j)*16 + fr)*32 + fp8];        \
            _Pragma("unroll")                                                \
            for (int i = 0; i < IM; i++)                                     \
                _Pragma("unroll")                                            \
                for (int j = 0; j < 4; j++)                                  \
                    acc[i][g2*4+j] = __builtin_amdgcn_mfma_f32_16x16x32_bf16(\
                                    af[i], bff[j], acc[i][g2*4+j], 0, 0, 0); \
        }                                                                    \
    }

    // prologue: tile 0 -> buf 0, drain, barrier
    ISSUE_TILE(0);
    __builtin_amdgcn_s_waitcnt(0x0F70);            // vmcnt(0)
    __builtin_amdgcn_s_barrier();

#pragma unroll 1
    for (int tau = 0; tau < T; ++tau) {
        if (tau + 1 < T) ISSUE_TILE((tau + 1) & 1);
        COMPUTE(tau & 1);
        if (tau + 1 < T) {
            __builtin_amdgcn_s_waitcnt(0x0F70);    // t+1 landed (hidden)
            __builtin_amdgcn_s_barrier();          // WAR + visibility
        }
    }

#undef COMPUTE
#undef ISSUE_TILE

    // epilogue: C[row, col], col = lane&15, row = (lane>>4)*4 + r (m89 layout)
    const int ccol  = lane & 15;
    const int crow4 = (lane >> 4) * 4;
#pragma unroll
    for (int j = 0; j < JN; j++) {
        int col = n0 + wn*(TN/2) + j*16 + ccol;
        float bj = bias[col];
#pragma unroll
        for (int i = 0; i < IM; i++) {
#pragma unroll
            for (int r = 0; r < 4; r++) {
                int row = m0 + wm*(TM/2) + i*16 + crow4 + r;
                float v = acc[i][j][r] + bj;
                v = v >= 0.f ? v : 0.01f * v;
                Cout[(size_t)row * N + col] = (bf16_t)v;
            }
        }
    }
}

// ---- final discretized-logistic NLL reduction ----
__global__ __launch_bounds__(256)
void reduce_nll(const float* __restrict__ S, const float* __restrict__ mean,
                const float* __restrict__ log_scale, float* __restrict__ out)
{
    float local = 0.f;
    const int total = BQ * DD;
    for (int idx = blockIdx.x * blockDim.x + threadIdx.x; idx < total;
         idx += gridDim.x * blockDim.x) {
        int j = idx & (DD - 1);
        float z  = S[idx];
        float mu = mean[j];
        float sc = expf(log_scale[j]);
        float ua = (z + 0.5f - mu) / sc;
        float ub = (z - 0.5f - mu) / sc;
        float la = fminf(ua, 0.f) - log1pf(expf(-fabsf(ua)));
        float lb = fminf(ub, 0.f) - log1pf(expf(-fabsf(ub)));
        float lp = la + logf(1.0f - expf(lb - la) + 1e-8f);
        local += lp;
    }
    __shared__ float red[256];
    red[threadIdx.x] = local;
    __syncthreads();
    for (int s = 128; s > 0; s >>= 1) {
        if (threadIdx.x < s) red[threadIdx.x] += red[threadIdx.x + s];
        __syncthreads();
    }
    if (threadIdx.x == 0) atomicAdd(out, -red[0] * (1.0f / (float)BQ));
}

extern "C" void kernel_launch(void* const* d_in, const int* in_sizes, int n_in,
                              void* d_out, int out_size, void* d_ws, size_t ws_size,
                              hipStream_t stream)
{
    const float* x   = (const float*)d_in[0];
    const float* W1  = (const float*)d_in[1];
    const float* b1  = (const float*)d_in[2];
    const float* W2  = (const float*)d_in[3];
    const float* b2  = (const float*)d_in[4];
    const float* W3  = (const float*)d_in[5];
    const float* b3  = (const float*)d_in[6];
    const float* mean = (const float*)d_in[7];
    const float* lsc  = (const float*)d_in[8];

    char* ws = (char*)d_ws;
    bf16_t* Wt1 = (bf16_t*)ws; ws += (size_t)NF * NH * D2 * 2;   // 16 MB (NxK = 2048x512)
    bf16_t* Wt2 = (bf16_t*)ws; ws += (size_t)NF * NH * NH * 2;   // 64 MB
    bf16_t* Wt3 = (bf16_t*)ws; ws += (size_t)NF * D2 * NH * 2;   // 16 MB (512x2048)
    float*  S   = (float*)ws;  ws += (size_t)BQ * DD * 4;        // 32 MB
    bf16_t* Ab  = (bf16_t*)ws; ws += (size_t)BQ * D2 * 2;        //  8 MB
    bf16_t* H1  = (bf16_t*)ws; ws += (size_t)BQ * NH * 2;        // 32 MB
    bf16_t* H2  = (bf16_t*)ws;                                   // 32 MB  (total 200 MB)

    hipMemsetAsync(d_out, 0, sizeof(float), stream);

    dim3 blk(256);
    // W1: (K=512, N=2048) -> Wt1 (2048x512)
    transpose_bf16<<<dim3(NH/32, D2/32, NF), blk, 0, stream>>>(W1, Wt1, D2, NH);
    // W2: (2048, 2048)
    transpose_bf16<<<dim3(NH/32, NH/32, NF), blk, 0, stream>>>(W2, Wt2, NH, NH);
    // W3: (K=2048, N=512) -> Wt3 (512x2048)
    transpose_bf16<<<dim3(D2/32, NH/32, NF), blk, 0, stream>>>(W3, Wt3, NH, D2);

    init_SA<<<BQ * DD / 4 / 256, blk, 0, stream>>>((const float4*)x, (float4*)S, Ab);

    for (int f = 0; f < NF; ++f) {
        int r = f & 1;
        // G1: (8192 x 512) @ (512 x 2048) -> H1   [128x128 2-buf, 1024 blocks]
        gemm2b_kernel<D2, 128, 128><<<dim3(NH/128, BQ/128), blk, 0, stream>>>(
            Ab, Wt1 + (size_t)f * NH * D2, b1 + (size_t)f * NH, H1, NH);
        // G2: (8192 x 2048) @ (2048 x 2048) -> H2 [128x128 2-buf, 1024 blocks]
        gemm2b_kernel<NH, 128, 128><<<dim3(NH/128, BQ/128), blk, 0, stream>>>(
            H1, Wt2 + (size_t)f * NH * NH, b2 + (size_t)f * NH, H2, NH);
        // G3: (8192 x 2048) @ (2048 x 512), 64x128 ring-3 -> S + next-A emit
        gemm_kernel<1, NH, 64, 128, 3><<<dim3(D2/128, BQ/64), blk, 0, stream>>>(
            H2, Wt3 + (size_t)f * D2 * NH, b3 + (size_t)f * D2, nullptr, S,
            Ab, D2, r);
    }

    reduce_nll<<<2048, blk, 0, stream>>>(S, mean, lsc, (float*)d_out);
}

// Round 5
// 1509.865 us; speedup vs baseline: 1.1694x; 1.0509x over previous
//
#include <hip/hip_runtime.h>
#include <hip/hip_bf16.h>
#include <cmath>

// ---------------------------------------------------------------------------
// IntegerDiscreteFlow on MI355X (gfx950)
// B=8192, D=1024, d2=512, N=2048, F=8 steps.
// State S (8192x1024 f32) updated in place; the [:, ::-1] reversal is an
// orientation bit (logical j <-> stored 1023-j), flipped each step.
// GEMMs in bf16 MFMA 16x16x32, fp32 accumulate.
// R2: XOR-swizzled LDS placement (bank conflicts -> 0).
// R5: ring-3 LDS pipeline (counted vmcnt across raw s_barrier).
// R6: 128x256 block tile for G1/G2 (wave-tile 64x128, 32 MFMA per barrier
//     per wave), 72 KB LDS, 2 blocks/CU. Proven 82.6 us G2 (832 TF).
// R7-R10: 8-phase ports and occupancy experiments all landed <= R6 (the
//     2-barrier family ceiling is ~830 TF regardless of waves/CU; occupancy
//     x2 at 128x128 gave +0% MfmaUtil). G1/G2 locked at R6 config.
// R11: G3 (M=8192,N=512,K=2048; was ~65 us at 64x128, ~265 TF) -> split-K=2:
//     two K-halves of 1024 on the ring-3 schedule at 128x128 tiles (16
//     MFMA/wave/barrier, grid (4,64,2)=512 blocks=2/CU, same regime as R6
//     G2). f32 partials alias H1 (free between G2 and next G1; 2x16MB fits
//     exactly). g3_epilogue sums partials+bias, rint, updates S, emits Ab.
//     Ring-3 tail generalized to (T-1)%3==1 (T=32).
// ---------------------------------------------------------------------------

typedef __bf16 bf16_t;
typedef bf16_t bf16x4 __attribute__((ext_vector_type(4)));
typedef bf16_t bf16x8 __attribute__((ext_vector_type(8)));
typedef float floatx4 __attribute__((ext_vector_type(4)));

#define BQ 8192
#define DD 1024
#define D2 512
#define NH 2048
#define NF 8

__device__ __forceinline__ void gload_lds16(const void* g, void* l) {
    __builtin_amdgcn_global_load_lds(
        (__attribute__((address_space(1))) void*)g,
        (__attribute__((address_space(3))) void*)l, 16, 0, 0);
}

// ---- weight convert+transpose: W (K x N f32, row-major) -> Wt (N x K bf16) --
__global__ __launch_bounds__(256)
void transpose_bf16(const float* __restrict__ W, bf16_t* __restrict__ Wt,
                    int K, int N) {
    __shared__ float tile[32][33];
    size_t fo = (size_t)blockIdx.z * K * N;
    int n0 = blockIdx.x * 32, k0 = blockIdx.y * 32;
    int tx = threadIdx.x & 31, ty = threadIdx.x >> 5;   // 32 x 8
    for (int i = 0; i < 4; i++)
        tile[ty + i*8][tx] = W[fo + (size_t)(k0 + ty + i*8) * N + n0 + tx];
    __syncthreads();
    for (int i = 0; i < 4; i++)
        Wt[fo + (size_t)(n0 + ty + i*8) * K + k0 + tx] = (bf16_t)tile[tx][ty + i*8];
}

// ---- fused: S = x (f32 copy) and Ab = bf16(xa) for step 0 ----
__global__ __launch_bounds__(256)
void init_SA(const float4* __restrict__ x, float4* __restrict__ S,
             bf16_t* __restrict__ Ab) {
    int idx = blockIdx.x * blockDim.x + threadIdx.x;   // over BQ*DD/4 = 2M
    float4 v = x[idx];
    S[idx] = v;
    int col4 = idx & (DD/4 - 1);                       // 0..255 (j = col4*4)
    if (col4 < D2/4) {
        int m = idx >> 8;
        bf16x4 p;
        p[0] = (bf16_t)v.x; p[1] = (bf16_t)v.y;
        p[2] = (bf16_t)v.z; p[3] = (bf16_t)v.w;
        ((bf16x4*)Ab)[(size_t)m * (D2/4) + col4] = p;
    }
}

// ---- GEMM, ring-3 LDS pipeline ----
// Block tile TM x TN, BK=32, 4 waves (2x2), wave-tile (TM/2) x (TN/2).
// KSTR = row stride of A/Bt; KDEP = K-depth this block accumulates
// (split-K: blockIdx.z selects the K-chunk at z*KDEP).
// MODE 0: Cout = bf16( leaky_relu(acc + bias[n]) )          (z must be 0)
// MODE 2: Pout[z*BQ*N + m*N + n] = acc  (f32 partial, no bias)
template<int MODE, int KSTR, int KDEP, int TM, int TN, int MINW>
__global__ __launch_bounds__(256, MINW)
void gemm_kernel(const bf16_t* __restrict__ A, const bf16_t* __restrict__ Bt,
                 const float* __restrict__ bias,
                 bf16_t* __restrict__ Cout, float* __restrict__ Pout,
                 int N)
{
    constexpr int IM   = TM / 32;          // i-fragments per wave
    constexpr int JN   = TN / 32;          // j-fragments per wave
    constexpr int NA   = TM / 64;          // A DMA instrs per tile
    constexpr int NBD  = TN / 64;          // B DMA instrs per tile
    constexpr int NDMA = NA + NBD;         // DMA instrs per tile
    constexpr int T    = KDEP / 32;        // K-tiles
    constexpr int REM  = (T - 1) % 3;      // leftover pipeline steps
    static_assert(REM == 0 || REM == 1, "tail handles rem 0/1 only");
    static_assert(JN % 4 == 0, "bff processed in groups of 4");

    __shared__ __align__(16) bf16_t As[3][TM * 32];
    __shared__ __align__(16) bf16_t Bs[3][TN * 32];

    const int tid  = threadIdx.x;
    const int lane = tid & 63;
    const int wave = tid >> 6;
    const int wm   = wave >> 1;            // 0..1
    const int wn   = wave & 1;             // 0..1
    const int m0   = blockIdx.y * TM;
    const int n0   = blockIdx.x * TN;
    const int koff = (MODE == 2) ? blockIdx.z * KDEP : 0;

    const int srow = tid >> 2;
    const int sq   = ((tid & 3) ^ ((srow >> 1) & 3)) * 8;
    const bf16_t* agp = A  + (size_t)(m0 + srow) * KSTR + koff + sq;
    const bf16_t* bgp = Bt + (size_t)(n0 + srow) * KSTR + koff + sq;

    floatx4 acc[IM][JN];
#pragma unroll
    for (int i = 0; i < IM; i++)
#pragma unroll
        for (int j = 0; j < JN; j++)
            acc[i][j] = (floatx4){0.f, 0.f, 0.f, 0.f};

    const int fr  = lane & 15;
    const int fp8 = ((lane >> 4) ^ ((lane >> 1) & 3)) * 8;

#define ISSUE_TILE(NB)                                                       \
    {                                                                        \
        _Pragma("unroll")                                                    \
        for (int u = 0; u < NA; u++)                                         \
            gload_lds16(agp + (size_t)(u*64) * KSTR, &As[NB][u*2048 + tid*8]);\
        _Pragma("unroll")                                                    \
        for (int u = 0; u < NBD; u++)                                        \
            gload_lds16(bgp + (size_t)(u*64) * KSTR, &Bs[NB][u*2048 + tid*8]);\
        agp += 32; bgp += 32;                                                \
    }

#define COMPUTE(CB)                                                          \
    {                                                                        \
        bf16x8 af[IM];                                                       \
        _Pragma("unroll")                                                    \
        for (int i = 0; i < IM; i++)                                         \
            af[i] = *(const bf16x8*)&As[CB][(wm*(TM/2) + i*16 + fr)*32 + fp8];\
        _Pragma("unroll")                                                    \
        for (int g2 = 0; g2 < JN/4; g2++) {                                  \
            bf16x8 bff[4];                                                   \
            _Pragma("unroll")                                                \
            for (int j = 0; j < 4; j++)                                      \
                bff[j] = *(const bf16x8*)                                    \
                    &Bs[CB][(wn*(TN/2) + (g2*4+j)*16 + fr)*32 + fp8];        \
            _Pragma("unroll")                                                \
            for (int i = 0; i < IM; i++)                                     \
                _Pragma("unroll")                                            \
                for (int j = 0; j < 4; j++)                                  \
                    acc[i][g2*4+j] = __builtin_amdgcn_mfma_f32_16x16x32_bf16(\
                                    af[i], bff[j], acc[i][g2*4+j], 0, 0, 0); \
        }                                                                    \
    }

#define PIPE_STEP(NB, CB)                                                    \
    {                                                                        \
        ISSUE_TILE(NB);                                                      \
        __builtin_amdgcn_s_waitcnt(0x0F70 | NDMA);  /* prev tile landed */   \
        __builtin_amdgcn_s_barrier();                                        \
        COMPUTE(CB);                                                         \
    }

    // prologue: tile 0 -> buf 0
    ISSUE_TILE(0);

    // steady state: tiles 3g+1, 3g+2, 3g+3 -> bufs 1, 2, 0
#pragma unroll 1
    for (int g = 0; g < (T - 1) / 3; ++g) {
        PIPE_STEP(1, 0);
        PIPE_STEP(2, 1);
        PIPE_STEP(0, 2);
    }
    // leftover: one more pipeline step (tile T-1 -> buf 1, compute buf 0)
    if constexpr (REM == 1) { PIPE_STEP(1, 0); }
    // tail: compute tile T-1, which lives in buf (T-1)%3
    __builtin_amdgcn_s_waitcnt(0x0F70);            // vmcnt(0)
    __builtin_amdgcn_s_barrier();
    COMPUTE(REM == 1 ? 1 : 0);

#undef PIPE_STEP
#undef COMPUTE
#undef ISSUE_TILE

    // epilogue: C[row, col], col = lane&15, row = (lane>>4)*4 + r (m89 layout)
    const int ccol  = lane & 15;
    const int crow4 = (lane >> 4) * 4;
#pragma unroll
    for (int j = 0; j < JN; j++) {
        int col = n0 + wn*(TN/2) + j*16 + ccol;
        if (MODE == 0) {
            float bj = bias[col];
#pragma unroll
            for (int i = 0; i < IM; i++) {
#pragma unroll
                for (int r = 0; r < 4; r++) {
                    int row = m0 + wm*(TM/2) + i*16 + crow4 + r;
                    float v = acc[i][j][r] + bj;
                    v = v >= 0.f ? v : 0.01f * v;
                    Cout[(size_t)row * N + col] = (bf16_t)v;
                }
            }
        } else {
            float* P = Pout + (size_t)blockIdx.z * BQ * N;
#pragma unroll
            for (int i = 0; i < IM; i++) {
#pragma unroll
                for (int r = 0; r < 4; r++) {
                    int row = m0 + wm*(TM/2) + i*16 + crow4 + r;
                    P[(size_t)row * N + col] = acc[i][j][r];
                }
            }
        }
    }
}

// ---- G3 epilogue: t = P0 + P1 + b3; S[slot] += rint(t); Ab = reverse ----
__global__ __launch_bounds__(256)
void g3_epilogue(const float* __restrict__ P, const float* __restrict__ b3,
                 float* __restrict__ S, bf16_t* __restrict__ Ab, int rflag)
{
    int idx = blockIdx.x * blockDim.x + threadIdx.x;   // over BQ*D2/4 = 1M
    int row = idx >> 7;                                // D2/4 = 128 per row
    int c4  = (idx & 127) * 4;
    float4 p0 = ((const float4*)P)[idx];
    float4 p1 = ((const float4*)(P + (size_t)BQ * D2))[idx];
    float4 bb = ((const float4*)b3)[idx & 127];
    float t0 = p0.x + p1.x + bb.x;
    float t1 = p0.y + p1.y + bb.y;
    float t2 = p0.z + p1.z + bb.z;
    float t3 = p0.w + p1.w + bb.w;
    const float tv[4] = {t0, t1, t2, t3};
#pragma unroll
    for (int e = 0; e < 4; ++e) {
        int col  = c4 + e;
        int slot = rflag ? (511 - col) : (512 + col);
        float nv = S[(size_t)row * DD + slot] + rintf(tv[e]);
        S[(size_t)row * DD + slot] = nv;
        Ab[(size_t)row * D2 + (511 - col)] = (bf16_t)nv;
    }
}

// ---- final discretized-logistic NLL reduction ----
__global__ __launch_bounds__(256)
void reduce_nll(const float* __restrict__ S, const float* __restrict__ mean,
                const float* __restrict__ log_scale, float* __restrict__ out)
{
    float local = 0.f;
    const int total = BQ * DD;
    for (int idx = blockIdx.x * blockDim.x + threadIdx.x; idx < total;
         idx += gridDim.x * blockDim.x) {
        int j = idx & (DD - 1);
        float z  = S[idx];
        float mu = mean[j];
        float sc = expf(log_scale[j]);
        float ua = (z + 0.5f - mu) / sc;
        float ub = (z - 0.5f - mu) / sc;
        float la = fminf(ua, 0.f) - log1pf(expf(-fabsf(ua)));
        float lb = fminf(ub, 0.f) - log1pf(expf(-fabsf(ub)));
        float lp = la + logf(1.0f - expf(lb - la) + 1e-8f);
        local += lp;
    }
    __shared__ float red[256];
    red[threadIdx.x] = local;
    __syncthreads();
    for (int s = 128; s > 0; s >>= 1) {
        if (threadIdx.x < s) red[threadIdx.x] += red[threadIdx.x + s];
        __syncthreads();
    }
    if (threadIdx.x == 0) atomicAdd(out, -red[0] * (1.0f / (float)BQ));
}

extern "C" void kernel_launch(void* const* d_in, const int* in_sizes, int n_in,
                              void* d_out, int out_size, void* d_ws, size_t ws_size,
                              hipStream_t stream)
{
    const float* x   = (const float*)d_in[0];
    const float* W1  = (const float*)d_in[1];
    const float* b1  = (const float*)d_in[2];
    const float* W2  = (const float*)d_in[3];
    const float* b2  = (const float*)d_in[4];
    const float* W3  = (const float*)d_in[5];
    const float* b3  = (const float*)d_in[6];
    const float* mean = (const float*)d_in[7];
    const float* lsc  = (const float*)d_in[8];

    char* ws = (char*)d_ws;
    bf16_t* Wt1 = (bf16_t*)ws; ws += (size_t)NF * NH * D2 * 2;   // 16 MB (NxK = 2048x512)
    bf16_t* Wt2 = (bf16_t*)ws; ws += (size_t)NF * NH * NH * 2;   // 64 MB
    bf16_t* Wt3 = (bf16_t*)ws; ws += (size_t)NF * D2 * NH * 2;   // 16 MB (512x2048)
    float*  S   = (float*)ws;  ws += (size_t)BQ * DD * 4;        // 32 MB
    bf16_t* Ab  = (bf16_t*)ws; ws += (size_t)BQ * D2 * 2;        //  8 MB
    bf16_t* H1  = (bf16_t*)ws; ws += (size_t)BQ * NH * 2;        // 32 MB
    bf16_t* H2  = (bf16_t*)ws;                                   // 32 MB  (total 200 MB)
    float*  P3  = (float*)H1;   // G3 split-K partials (2 x 16 MB) alias H1:
                                // H1 is dead between G2 (reads it) and the
                                // next step's G1 (writes it).

    hipMemsetAsync(d_out, 0, sizeof(float), stream);

    dim3 blk(256);
    // W1: (K=512, N=2048) -> Wt1 (2048x512)
    transpose_bf16<<<dim3(NH/32, D2/32, NF), blk, 0, stream>>>(W1, Wt1, D2, NH);
    // W2: (2048, 2048)
    transpose_bf16<<<dim3(NH/32, NH/32, NF), blk, 0, stream>>>(W2, Wt2, NH, NH);
    // W3: (K=2048, N=512) -> Wt3 (512x2048)
    transpose_bf16<<<dim3(D2/32, NH/32, NF), blk, 0, stream>>>(W3, Wt3, NH, D2);

    init_SA<<<BQ * DD / 4 / 256, blk, 0, stream>>>((const float4*)x, (float4*)S, Ab);

    for (int f = 0; f < NF; ++f) {
        int r = f & 1;
        // G1: (8192 x 512) @ (512 x 2048) -> H1   [128x256 ring-3, 512 blocks]
        gemm_kernel<0, D2, D2, 128, 256, 2><<<dim3(NH/256, BQ/128), blk, 0, stream>>>(
            Ab, Wt1 + (size_t)f * NH * D2, b1 + (size_t)f * NH, H1, nullptr, NH);
        // G2: (8192 x 2048) @ (2048 x 2048) -> H2 [128x256 ring-3, 512 blocks]
        gemm_kernel<0, NH, NH, 128, 256, 2><<<dim3(NH/256, BQ/128), blk, 0, stream>>>(
            H1, Wt2 + (size_t)f * NH * NH, b2 + (size_t)f * NH, H2, nullptr, NH);
        // G3: (8192 x 2048) @ (2048 x 512) split-K=2, 128x128 ring-3,
        //     grid (4,64,2) = 512 blocks; f32 partials -> P3 (aliases H1)
        gemm_kernel<2, NH, 1024, 128, 128, 2><<<dim3(D2/128, BQ/128, 2), blk, 0, stream>>>(
            H2, Wt3 + (size_t)f * D2 * NH, nullptr, nullptr, P3, D2);
        // G3 epilogue: sum partials + bias, rint, update S, emit next A
        g3_epilogue<<<BQ * D2 / 4 / 256, blk, 0, stream>>>(
            P3, b3 + (size_t)f * D2, S, Ab, r);
    }

    reduce_nll<<<2048, blk, 0, stream>>>(S, mean, lsc, (float*)d_out);
}